// Round 6
// baseline (367.287 us; speedup 1.0000x reference)
//
#include <hip/hip_runtime.h>

// SignMaskLinear: out[t,o] = sum_k x[t,k] * sign(W[o,k]) + b[o]
// i8 path: W ternary {-1,0,1} is EXACT in i8. x quantized per-row
// (symmetric, scale = rowmax/127). out = i32acc * scale[row] + bias[col].
//
// R6: ELIMINATE the xq round-trip. R3/R5 post-mortems: three different
// K-loop schedules all ±4% -> schedule is not the constraint; the 2-dispatch
// dataflow (read x 128MB, write xq 32MB, drain, re-read xq) is. New shape:
// grid = m-stripes (M/128 = 256 blocks, 1/CU). Each block quantizes its own
// 128-row stripe INTO LDS (one pass over x, registers retained between
// absmax and quantize — no global xq, no scales buffer, no 2nd big kernel),
// then runs all n-tiles x K-steps against it. Only B (wq, 1MB, L2-resident)
// is staged per K-step (global_load_lds dbuf + counted vmcnt(2)).
// HBM floor: x 128MB read + C 128MB write ~= 41us. MFMA floor 15.6us.
// GEMM fragment core = R3-verified (absmax 1.625 oracle).

typedef int   i32x4  __attribute__((ext_vector_type(4)));
typedef int   i32x16 __attribute__((ext_vector_type(16)));
typedef float f32x4  __attribute__((ext_vector_type(4)));

#define BM 128
#define BN 128
#define BK 64

__device__ __forceinline__ void async16(const void* gptr, void* lptr) {
    __builtin_amdgcn_global_load_lds(
        (const __attribute__((address_space(1))) unsigned int*)gptr,
        (__attribute__((address_space(3))) unsigned int*)lptr,
        16, 0, 0);
}

__device__ __forceinline__ int clamp127(int v) {
    v = v > 127 ? 127 : v;
    v = v < -127 ? -127 : v;
    return v;
}

__device__ __forceinline__ int pack4(int a, int b, int c, int d) {
    return (a & 255) | ((b & 255) << 8) | ((c & 255) << 16) | ((d & 255) << 24);
}

__device__ __forceinline__ int sgnb(float v) {
    return (v > 0.0f) ? 1 : ((v < 0.0f) ? -1 : 0);
}

__device__ __forceinline__ float max4(float4 v) {
    return fmaxf(fmaxf(fabsf(v.x), fabsf(v.y)), fmaxf(fabsf(v.z), fabsf(v.w)));
}

__device__ __forceinline__ int q4(float4 v, float inv) {
    return pack4(clamp127(__float2int_rn(v.x * inv)),
                 clamp127(__float2int_rn(v.y * inv)),
                 clamp127(__float2int_rn(v.z * inv)),
                 clamp127(__float2int_rn(v.w * inv)));
}

// ---- W sign prepass (tiny: 4MB read, 1MB write) -------------------------

__global__ __launch_bounds__(256)
void wsign_kernel(const float* __restrict__ w, signed char* __restrict__ wq,
                  long nw) {
    long i = ((long)blockIdx.x * 256 + threadIdx.x) * 8;
    if (i + 8 > nw) return;
    const float4* p = (const float4*)(w + i);
    float4 a = p[0];
    float4 b = p[1];
    int lo = pack4(sgnb(a.x), sgnb(a.y), sgnb(a.z), sgnb(a.w));
    int hi = pack4(sgnb(b.x), sgnb(b.y), sgnb(b.z), sgnb(b.w));
    int2 v; v.x = lo; v.y = hi;
    *(int2*)(wq + i) = v;
}

// ---- fused quant + GEMM -------------------------------------------------
// Block = one 128-row m-stripe. K == 1024 (fast-gate).
//
// A-LDS: [128 rows][1024 B]; 16B chunk c of row r stored at c' = c ^ (r&15)
// (bijective; read side: 32 lanes/frag span rows r..r+31 -> 16 slots x 2
// lanes = free 2-way). Written by ds_write_b128 (normal store — no
// global_load_lds constraint), read by MFMA frag loads with the same XOR.
//
// B-LDS: 2 x [64 lds-rows][128B] dbuf, staged via global_load_lds with
// pre-swizzled global source (R3-verified both-sides swizzle).
//
// K-loop: flattened s = nt*16 + ks over (n-tile, K-step). Per iter:
//   STAGEB(s+1) ; vmcnt(2) ; barrier ; COMPUTE(buf s&1) ;
//   [tile end: EPILOGUE + acc reset] ; barrier.
// vmcnt(2) keeps next tile's 2 loads in flight (never drains mid-loop,
// except the once-per-n-tile epilogue-store drain — 8x/kernel, accepted).

__global__ __launch_bounds__(256)
void gemm_fused(const float* __restrict__ x, const signed char* __restrict__ B,
                const float* __restrict__ bias, float* __restrict__ C,
                int N, int K) {
    __shared__ __align__(16) signed char sA[BM * 1024];   // 128 KB
    __shared__ __align__(16) signed char sB[2 * 64 * 128]; // 16 KB
    __shared__ float s_scales[BM];                         // 0.5 KB

    const int tid  = threadIdx.x;
    const int lane = tid & 63;
    const int wave = tid >> 6;
    const int bm   = blockIdx.x * BM;

    // ---- B staging addresses issued early (B[0] flies during phase 1) ----
    const int s0 = tid, s1 = tid + 256;
    const int lr0 = s0 >> 3, lr1 = s1 >> 3;
    const int cc0 = (s0 & 7) ^ (lr0 & 7);
    const int cc1 = (s1 & 7) ^ (lr1 & 7);
    const long offB0 = (long)((cc0 >> 2) * 64 + lr0) * K + (cc0 & 3) * 16;
    const long offB1 = (long)((cc1 >> 2) * 64 + lr1) * K + (cc1 & 3) * 16;
    const int d0 = s0 * 16, d1 = s1 * 16;

#define STAGEB(bb, s2)                                                   \
    do {                                                                 \
        const int nt2 = (s2) >> 4, ks2 = (s2) & 15;                      \
        const signed char* bp = B + (long)nt2 * 128 * K + ks2 * 64;      \
        async16(bp + offB0, (char*)sB + (bb) * 8192 + d0);               \
        async16(bp + offB1, (char*)sB + (bb) * 8192 + d1);               \
    } while (0)

    STAGEB(0, 0);

    // ---- phase 1: quantize this block's 128-row stripe into LDS ----------
    // wave wv owns rows [wv*32, wv*32+32). Lane l holds 16 consecutive
    // floats (64 B) of the row -> absmax via 6-step shuffle -> quantize the
    // retained regs -> one swizzled ds_write_b128.
    {
        const int rbase = wave * 32;
#pragma unroll 4
        for (int rr = 0; rr < 32; rr += 2) {
            const int ra = rbase + rr, rb = ra + 1;
            const float4* pa = (const float4*)(x + (long)(bm + ra) * K + lane * 16);
            const float4* pb = (const float4*)(x + (long)(bm + rb) * K + lane * 16);
            float4 a0 = pa[0], a1 = pa[1], a2 = pa[2], a3 = pa[3];
            float4 b0 = pb[0], b1 = pb[1], b2 = pb[2], b3 = pb[3];
            float ma = fmaxf(fmaxf(max4(a0), max4(a1)), fmaxf(max4(a2), max4(a3)));
            float mb = fmaxf(fmaxf(max4(b0), max4(b1)), fmaxf(max4(b2), max4(b3)));
#pragma unroll
            for (int off = 32; off > 0; off >>= 1) {
                ma = fmaxf(ma, __shfl_xor(ma, off, 64));
                mb = fmaxf(mb, __shfl_xor(mb, off, 64));
            }
            const float ia = (ma > 0.0f) ? (127.0f / ma) : 0.0f;
            const float ib = (mb > 0.0f) ? (127.0f / mb) : 0.0f;
            i32x4 qa, qb;
            qa[0] = q4(a0, ia); qa[1] = q4(a1, ia); qa[2] = q4(a2, ia); qa[3] = q4(a3, ia);
            qb[0] = q4(b0, ib); qb[1] = q4(b1, ib); qb[2] = q4(b2, ib); qb[3] = q4(b3, ib);
            *(i32x4*)&sA[ra * 1024 + ((lane ^ (ra & 15)) << 4)] = qa;
            *(i32x4*)&sA[rb * 1024 + ((lane ^ (rb & 15)) << 4)] = qb;
            if (lane == 0) {
                s_scales[ra] = ma * (1.0f / 127.0f);
                s_scales[rb] = mb * (1.0f / 127.0f);
            }
        }
    }
    __syncthreads();   // A-LDS + scales complete

    // ---- phase 2: all n-tiles x K-steps against the persistent A stripe --
    const int wrow = (wave >> 1) * 64;
    const int wcol = (wave & 1) * 64;
    const int l31  = lane & 31;
    const int ksel = lane >> 5;
    const int halfB = wave & 1;
    const int lx   = l31 & 15;

    const int rowA0 = (wrow + l31) * 1024;
    const int rowA1 = rowA0 + 32 * 1024;

    const int rsw  = (l31 & 7) << 4;
    const int ccB0 = (halfB * 4 + 0 + ksel) << 4;   // kk=0
    const int ccB1 = (halfB * 4 + 2 + ksel) << 4;   // kk=1
    const int rB0  = l31 * 128;
    const int rB1  = (32 + l31) * 128;
    const int oB00 = rB0 + (ccB0 ^ rsw);
    const int oB01 = rB0 + (ccB1 ^ rsw);
    const int oB10 = rB1 + (ccB0 ^ rsw);
    const int oB11 = rB1 + (ccB1 ^ rsw);

    const i32x16 zz = {};
    i32x16 acc00 = zz, acc01 = zz, acc10 = zz, acc11 = zz;

    // swapped operands: mfma(B_frag, A_frag, acc) -> D[n_local][m_local];
    // m_local = l31, n_local = (reg&3) + 8*(reg>>2) + 4*ksel.
#define COMPUTE(ks, bb)                                                       \
    do {                                                                      \
        const signed char* b_ = sB + (bb) * 8192;                             \
        const int c0 = (ks) * 4 + ksel;                                       \
        const int c1 = c0 + 2;                                                \
        i32x4 a0 = *(const i32x4*)&sA[rowA0 + ((c0 ^ lx) << 4)];              \
        i32x4 a1 = *(const i32x4*)&sA[rowA1 + ((c0 ^ lx) << 4)];              \
        i32x4 b0 = *(const i32x4*)(b_ + oB00);                                \
        i32x4 b1 = *(const i32x4*)(b_ + oB10);                                \
        acc00 = __builtin_amdgcn_mfma_i32_32x32x32_i8(b0, a0, acc00, 0, 0, 0);\
        acc01 = __builtin_amdgcn_mfma_i32_32x32x32_i8(b1, a0, acc01, 0, 0, 0);\
        acc10 = __builtin_amdgcn_mfma_i32_32x32x32_i8(b0, a1, acc10, 0, 0, 0);\
        acc11 = __builtin_amdgcn_mfma_i32_32x32x32_i8(b1, a1, acc11, 0, 0, 0);\
        a0 = *(const i32x4*)&sA[rowA0 + ((c1 ^ lx) << 4)];                    \
        a1 = *(const i32x4*)&sA[rowA1 + ((c1 ^ lx) << 4)];                    \
        b0 = *(const i32x4*)(b_ + oB01);                                      \
        b1 = *(const i32x4*)(b_ + oB11);                                      \
        acc00 = __builtin_amdgcn_mfma_i32_32x32x32_i8(b0, a0, acc00, 0, 0, 0);\
        acc01 = __builtin_amdgcn_mfma_i32_32x32x32_i8(b1, a0, acc01, 0, 0, 0);\
        acc10 = __builtin_amdgcn_mfma_i32_32x32x32_i8(b0, a1, acc10, 0, 0, 0);\
        acc11 = __builtin_amdgcn_mfma_i32_32x32x32_i8(b1, a1, acc11, 0, 0, 0);\
    } while (0)

#define STORE_FRAG(accv, i, j, nt)                                            \
    do {                                                                      \
        const int row = bm + wrow + (i) * 32 + l31;                           \
        const float sc = s_scales[wrow + (i) * 32 + l31];                     \
        const int cb = (nt) * 128 + wcol + (j) * 32;                          \
        float* cr = C + (long)row * N + cb;                                   \
        _Pragma("unroll")                                                     \
        for (int g = 0; g < 4; ++g) {                                         \
            const int n0 = g * 8 + ksel * 4;                                  \
            const f32x4 bv = *(const f32x4*)&bias[cb + n0];                   \
            f32x4 o;                                                          \
            o[0] = (float)(accv)[4 * g + 0] * sc + bv[0];                     \
            o[1] = (float)(accv)[4 * g + 1] * sc + bv[1];                     \
            o[2] = (float)(accv)[4 * g + 2] * sc + bv[2];                     \
            o[3] = (float)(accv)[4 * g + 3] * sc + bv[3];                     \
            *(f32x4*)&cr[n0] = o;                                             \
        }                                                                     \
    } while (0)

    const int total = (N / BN) * (K / BK);   // n-tile major, 16 K-steps each
    for (int s = 0; s < total; ++s) {
        const int bb = s & 1;
        if (s + 1 < total) {
            STAGEB(bb ^ 1, s + 1);
            asm volatile("s_waitcnt vmcnt(2)" ::: "memory");
        } else {
            asm volatile("s_waitcnt vmcnt(0)" ::: "memory");
        }
        __builtin_amdgcn_sched_barrier(0);
        __builtin_amdgcn_s_barrier();
        __builtin_amdgcn_sched_barrier(0);
        COMPUTE(s & 15, bb);
        if ((s & 15) == 15) {
            const int nt = s >> 4;
            STORE_FRAG(acc00, 0, 0, nt);
            STORE_FRAG(acc01, 0, 1, nt);
            STORE_FRAG(acc10, 1, 0, nt);
            STORE_FRAG(acc11, 1, 1, nt);
            acc00 = zz; acc01 = zz; acc10 = zz; acc11 = zz;
        }
        __builtin_amdgcn_s_barrier();
    }

#undef STAGEB
#undef COMPUTE
#undef STORE_FRAG
}

// ---- fallback (odd shapes) ----------------------------------------------

__device__ __forceinline__ float signf(float v) {
    return (v > 0.0f) ? 1.0f : ((v < 0.0f) ? -1.0f : 0.0f);
}

__global__ void fallback_kernel(const float* __restrict__ x, const float* __restrict__ w,
                                const float* __restrict__ b, float* __restrict__ out,
                                int M, int N, int K) {
    long o = (long)blockIdx.x * blockDim.x + threadIdx.x;
    if (o >= (long)M * N) return;
    int t = (int)(o / N);
    int n = (int)(o % N);
    const float* xr = x + (long)t * K;
    const float* wr = w + (long)n * K;
    float s = 0.0f;
    for (int k = 0; k < K; ++k) s += xr[k] * signf(wr[k]);
    out[o] = s + b[n];
}

// ---- launch -------------------------------------------------------------

extern "C" void kernel_launch(void* const* d_in, const int* in_sizes, int n_in,
                              void* d_out, int out_size, void* d_ws, size_t ws_size,
                              hipStream_t stream) {
    const float* x = (const float*)d_in[0];
    const float* w = (const float*)d_in[1];
    const float* b = (const float*)d_in[2];
    float* out = (float*)d_out;

    const int N = in_sizes[2];
    const int K = in_sizes[1] / N;
    const int M = in_sizes[0] / K;

    const long nw = (long)N * K;

    const bool fast = (K == 1024) && (M % BM == 0) && (N % BN == 0) &&
                      (nw % 2048 == 0) && (ws_size >= (size_t)nw);

    if (!fast) {
        long total = (long)M * N;
        int blocks = (int)((total + 255) / 256);
        fallback_kernel<<<blocks, 256, 0, stream>>>(x, w, b, out, M, N, K);
        return;
    }

    signed char* wq = (signed char*)d_ws;

    wsign_kernel<<<(int)(nw / 2048), 256, 0, stream>>>(w, wq, nw);
    gemm_fused<<<M / BM, 256, 0, stream>>>(x, wq, b, out, N, K);
}